// Round 5
// baseline (460.654 us; speedup 1.0000x reference)
//
#include <hip/hip_runtime.h>

// GCN on MI355X — round 5: kill k_fill's 8x write-sector amplification.
//  - Round-4 profile: k_fill 111 us, WRITE_SIZE 101 MB vs 12.8 MB logical
//    (random 8B scatter -> one dirty 64B sector per edge).
//  - Fix: two-phase bucketed counting sort. k_part streams edges once
//    (histogram + partition into 25 dst-buckets of 4096 nodes, LDS-ranked
//    block-chunked staging writes, ~330B runs). k_fine scatters within a
//    ~520KB per-bucket window (L2-contained, lines fill before eviction).
//  - Graph math + fused MLP unchanged from round 4.

#define HD 128
#define HD2 256
#define BSHIFT 12            // 4096 nodes per bucket; dstLocal fits 12 bits
#define SRCBITS 17           // N=100000 < 2^17

typedef __attribute__((ext_vector_type(8))) short bf8_t;   // 8 x bf16 (4 VGPR)
typedef __attribute__((ext_vector_type(4))) float f32x4;

static inline size_t align256(size_t x) { return (x + 255) & ~(size_t)255; }

__device__ inline ushort f2bf(float f) {            // RNE f32 -> bf16
    uint u = __float_as_uint(f);
    uint r = u + 0x7fffu + ((u >> 16) & 1u);
    return (ushort)(r >> 16);
}
__device__ inline float bflo(uint p) { return __uint_as_float(p << 16); }
__device__ inline float bfhi(uint p) { return __uint_as_float(p & 0xffff0000u); }
__device__ inline uint packbf(float a, float b) {
    return (uint)f2bf(a) | ((uint)f2bf(b) << 16);
}

// Phase 1: stream edges once. Histogram cnt[d], partition into buckets by
// dst>>12 with per-block LDS ranking; staging writes are block-chunked runs.
__global__ __launch_bounds__(256) void k_part(const int* __restrict__ ei,
                                              const float* __restrict__ ew,
                                              int* __restrict__ cnt,
                                              int* __restrict__ bfill,
                                              uint2* __restrict__ stg,
                                              int E, int nbuck, int cap) {
    __shared__ int lcnt[32];
    __shared__ int lbase[32];
    int tid = threadIdx.x;
    if (tid < nbuck) lcnt[tid] = 0;
    __syncthreads();
    bool is64 = (ei[1] == 0) && (ei[3] == 0) && (ei[5] == 0) && (ei[7] == 0);
    int e0 = blockIdx.x * 1024;
    uint pack[4]; uint wbits[4]; int bkt[4]; int rank[4];
    for (int u = 0; u < 4; u++) {
        int e = e0 + u * 256 + tid;
        bkt[u] = -1;
        if (e < E) {
            int s, d;
            if (is64) { s = ei[2 * e]; d = ei[2 * (E + e)]; }
            else      { s = ei[e];     d = ei[E + e]; }
            atomicAdd(&cnt[d], 1);
            bkt[u] = d >> BSHIFT;
            pack[u] = ((uint)(d & ((1 << BSHIFT) - 1)) << SRCBITS) | (uint)s;
            wbits[u] = __float_as_uint(ew[e]);
            rank[u] = atomicAdd(&lcnt[bkt[u]], 1);
        }
    }
    __syncthreads();
    if (tid < nbuck) lbase[tid] = atomicAdd(&bfill[tid], lcnt[tid]);
    __syncthreads();
    for (int u = 0; u < 4; u++)
        if (bkt[u] >= 0)
            stg[(size_t)bkt[u] * cap + lbase[bkt[u]] + rank[u]] =
                make_uint2(pack[u], wbits[u]);
}

// --- 3-kernel exclusive scan of cnt[0..N) -> rowptr[0..N] ---
__global__ __launch_bounds__(1024) void k_scan1(const int* __restrict__ cnt,
                                                int* __restrict__ incl,
                                                int* __restrict__ bsum, int N) {
    __shared__ int s[1024];
    int t = threadIdx.x, i = blockIdx.x * 1024 + t;
    s[t] = (i < N) ? cnt[i] : 0;
    __syncthreads();
    for (int off = 1; off < 1024; off <<= 1) {
        int add = (t >= off) ? s[t - off] : 0;
        __syncthreads();
        s[t] += add;
        __syncthreads();
    }
    if (i < N) incl[i] = s[t];
    if (t == 1023) bsum[blockIdx.x] = s[t];
}

__global__ void k_scan2(int* __restrict__ bsum, int nb) {
    __shared__ int s[1024];
    int t = threadIdx.x;
    for (int i = t; i < nb; i += blockDim.x) s[i] = bsum[i];
    __syncthreads();
    if (t == 0) {
        int run = 0;
        for (int i = 0; i < nb; i++) { int v = s[i]; s[i] = run; run += v; }
    }
    __syncthreads();
    for (int i = t; i < nb; i += blockDim.x) bsum[i] = s[i];
}

__global__ void k_scan3(const int* __restrict__ cnt, const int* __restrict__ incl,
                        const int* __restrict__ bsum, int* __restrict__ rowptr,
                        int* __restrict__ fill, int N, int E) {
    int i = blockIdx.x * blockDim.x + threadIdx.x;
    if (i < N) {
        rowptr[i] = bsum[i >> 10] + incl[i] - cnt[i];
        fill[i] = 0;
    }
    if (i == N) rowptr[N] = E;
}

// Phase 2: per-bucket fine scatter into cv. 64 blocks per bucket; destination
// window ~520KB stays in L2 so lines fill before eviction.
__global__ __launch_bounds__(256) void k_fine(const uint2* __restrict__ stg,
                                              const int* __restrict__ bfill,
                                              const int* __restrict__ rowptr,
                                              int* __restrict__ fill,
                                              int2* __restrict__ cv, int cap) {
    int b = blockIdx.x >> 6;
    int sub = blockIdx.x & 63;
    int n = bfill[b];
    const uint2* s = stg + (size_t)b * cap;
    for (int i = sub * 256 + threadIdx.x; i < n; i += 64 * 256) {
        uint2 r = s[i];
        int d = (b << BSHIFT) + (int)(r.x >> SRCBITS);
        int src = (int)(r.x & ((1u << SRCBITS) - 1));
        int pos = rowptr[d] + atomicAdd(&fill[d], 1);
        cv[pos] = make_int2(src, (int)r.y);
    }
}

// Pre-transpose weights to bf16 chunk layout Bt[(k>>3)*NCOLS*8 + n*8 + (k&7)].
__global__ void k_prepB(const float* __restrict__ W2, const float* __restrict__ Wl1,
                        ushort* __restrict__ Bt1, ushort* __restrict__ Bt2) {
    int o = blockIdx.x * blockDim.x + threadIdx.x;
    if (o >= 32768) return;
    {   // Bt1: K=128, NCOLS=256
        int k0 = o & 7, n = (o >> 3) & 255, k8 = o >> 11;
        Bt1[o] = f2bf(W2[(size_t)(k8 * 8 + k0) * 256 + n]);
    }
    {   // Bt2: K=256, NCOLS=128
        int k0 = o & 7, n = (o >> 3) & 127, k8 = o >> 10;
        Bt2[o] = f2bf(Wl1[(size_t)(k8 * 8 + k0) * 128 + n]);
    }
}

// Wave per node: deg = 1 + sum(row val); dis = rsqrt(deg); p = dis * x.
__global__ __launch_bounds__(256) void k_deg_dis_p(const int* __restrict__ rowptr,
                                                   const int2* __restrict__ cv,
                                                   const float* __restrict__ x,
                                                   float* __restrict__ dis,
                                                   float* __restrict__ p, int N) {
    int wid = (blockIdx.x * blockDim.x + threadIdx.x) >> 6;
    int lane = threadIdx.x & 63;
    if (wid >= N) return;
    int beg = rowptr[wid], end = rowptr[wid + 1];
    float s = 0.0f;
    for (int i = beg + lane; i < end; i += 64) s += __int_as_float(cv[i].y);
    for (int off = 32; off > 0; off >>= 1) s += __shfl_xor(s, off);
    if (lane == 0) {
        float r = rsqrtf(1.0f + s);
        dis[wid] = r;
        p[wid] = r * x[wid];
    }
}

// Wave per node, fused: q = sum(val*p[col]); t = dis*(q+p);
// g1[i][f] = dis * relu(t*W1[f]+b1[f]) stored bf16 (lane covers 2 feats).
__global__ __launch_bounds__(256) void k_q_g1(const int* __restrict__ rowptr,
                                              const int2* __restrict__ cv,
                                              const float* __restrict__ dis,
                                              const float* __restrict__ p,
                                              const float* __restrict__ W1,
                                              const float* __restrict__ b1,
                                              uint* __restrict__ g1, int N) {
    int wid = (blockIdx.x * blockDim.x + threadIdx.x) >> 6;
    int lane = threadIdx.x & 63;
    if (wid >= N) return;
    int beg = rowptr[wid], end = rowptr[wid + 1];
    float s = 0.0f;
    for (int i = beg + lane; i < end; i += 64) {
        int2 pr = cv[i];
        s += __int_as_float(pr.y) * p[pr.x];
    }
    for (int off = 32; off > 0; off >>= 1) s += __shfl_xor(s, off);
    float r = dis[wid];
    float t = r * (s + p[wid]);
    float2 wv = *(const float2*)(W1 + lane * 2);
    float2 bv = *(const float2*)(b1 + lane * 2);
    float ox = r * fmaxf(t * wv.x + bv.x, 0.0f);
    float oy = r * fmaxf(t * wv.y + bv.y, 0.0f);
    g1[(size_t)wid * 64 + lane] = packbf(ox, oy);
}

// Wave per node: z[d][:] = dis[d]*(sum_e w_e*g1[col_e][:] + g1[d][:]), bf16 io.
__global__ __launch_bounds__(256) void k_agg(const int* __restrict__ rowptr,
                                             const int2* __restrict__ cv,
                                             const float* __restrict__ dis,
                                             const uint* __restrict__ g1,
                                             uint* __restrict__ z, int N) {
    int wid = (blockIdx.x * blockDim.x + threadIdx.x) >> 6;
    int lane = threadIdx.x & 63;
    if (wid >= N) return;
    int beg = rowptr[wid], end = rowptr[wid + 1];
    float ax = 0.0f, ay = 0.0f;
    for (int base = beg; base < end; base += 64) {
        int eidx = base + lane;
        int2 pr = make_int2(0, 0);
        if (eidx < end) pr = cv[eidx];
        int cs = pr.x;
        float wv = __int_as_float(pr.y);
        int m = min(64, end - base);
        for (int j = 0; j < m; j++) {
            int s = __shfl(cs, j);
            float ww = __shfl(wv, j);
            uint gv = g1[(size_t)s * 64 + lane];
            ax += ww * bflo(gv);
            ay += ww * bfhi(gv);
        }
    }
    uint sv = g1[(size_t)wid * 64 + lane];
    float r = dis[wid];
    z[(size_t)wid * 64 + lane] = packbf(r * (ax + bflo(sv)), r * (ay + bfhi(sv)));
}

// Fused MLP: out[i] = relu(relu(z[i]@W2+b2)@Wl1+bl1) . wl2 + bl2.
// 4 independent waves/block, 32 rows each. h2 lives only in regs + per-wave LDS.
__global__ __launch_bounds__(256) void k_mlp(const ushort* __restrict__ A,    // z bf16 [N][128]
                                             const ushort* __restrict__ Bt1,  // [16][256][8]
                                             const ushort* __restrict__ Bt2,  // [32][128][8]
                                             const float* __restrict__ b2,
                                             const float* __restrict__ bl1,
                                             const float* __restrict__ wl2,
                                             const float* __restrict__ bl2,
                                             float* __restrict__ out, int M) {
    __shared__ ushort st[4][32][40];   // per-wave C->A staging; 80B row stride
    int tid = threadIdx.x;
    int wv = tid >> 6, lane = tid & 63;
    int l15 = lane & 15, quad = lane >> 4;
    int row0 = blockIdx.x * 128 + wv * 32;
    int r0 = row0 + l15;      r0 = r0 < M ? r0 : M - 1;   // clamp; stores guarded
    int r1 = row0 + 16 + l15; r1 = r1 < M ? r1 : M - 1;

    bf8_t a1[2][4];                       // all A1 frags resident (32 VGPR)
    for (int kc = 0; kc < 4; kc++) {
        a1[0][kc] = *(const bf8_t*)(A + (size_t)r0 * 128 + kc * 32 + quad * 8);
        a1[1][kc] = *(const bf8_t*)(A + (size_t)r1 * 128 + kc * 32 + quad * 8);
    }
    f32x4 acc2[2][8];
    for (int i = 0; i < 2; i++)
        for (int j = 0; j < 8; j++) acc2[i][j] = (f32x4){0.f, 0.f, 0.f, 0.f};

    for (int c = 0; c < 8; c++) {         // 32-col chunk of h2 == 32-k of GEMM2
        f32x4 acc1[2][2];
        for (int i = 0; i < 2; i++)
            for (int j = 0; j < 2; j++) acc1[i][j] = (f32x4){0.f, 0.f, 0.f, 0.f};
        for (int kc = 0; kc < 4; kc++)
            for (int nt = 0; nt < 2; nt++) {
                bf8_t b = *(const bf8_t*)(Bt1 +
                    ((size_t)(kc * 4 + quad) * 256 + c * 32 + nt * 16 + l15) * 8);
                acc1[0][nt] = __builtin_amdgcn_mfma_f32_16x16x32_bf16(a1[0][kc], b, acc1[0][nt], 0, 0, 0);
                acc1[1][nt] = __builtin_amdgcn_mfma_f32_16x16x32_bf16(a1[1][kc], b, acc1[1][nt], 0, 0, 0);
            }
        for (int nt = 0; nt < 2; nt++) {
            float bb = b2[c * 32 + nt * 16 + l15];
            for (int mt = 0; mt < 2; mt++)
                for (int rg = 0; rg < 4; rg++)
                    st[wv][mt * 16 + quad * 4 + rg][nt * 16 + l15] =
                        f2bf(fmaxf(acc1[mt][nt][rg] + bb, 0.f));
        }
        bf8_t a2_0 = *(const bf8_t*)&st[wv][l15][quad * 8];
        bf8_t a2_1 = *(const bf8_t*)&st[wv][16 + l15][quad * 8];
        for (int nt2 = 0; nt2 < 8; nt2++) {
            bf8_t b = *(const bf8_t*)(Bt2 +
                ((size_t)(c * 4 + quad) * 128 + nt2 * 16 + l15) * 8);
            acc2[0][nt2] = __builtin_amdgcn_mfma_f32_16x16x32_bf16(a2_0, b, acc2[0][nt2], 0, 0, 0);
            acc2[1][nt2] = __builtin_amdgcn_mfma_f32_16x16x32_bf16(a2_1, b, acc2[1][nt2], 0, 0, 0);
        }
    }
    float rs[2][4] = {};
    for (int nt2 = 0; nt2 < 8; nt2++) {
        int col = nt2 * 16 + l15;
        float bb = bl1[col], ww = wl2[col];
        for (int mt = 0; mt < 2; mt++)
            for (int rg = 0; rg < 4; rg++)
                rs[mt][rg] += fmaxf(acc2[mt][nt2][rg] + bb, 0.f) * ww;
    }
    float base = bl2[0];
    for (int mt = 0; mt < 2; mt++)
        for (int rg = 0; rg < 4; rg++) {
            float s = rs[mt][rg];
            s += __shfl_xor(s, 1);
            s += __shfl_xor(s, 2);
            s += __shfl_xor(s, 4);
            s += __shfl_xor(s, 8);
            int row = row0 + mt * 16 + quad * 4 + rg;
            if (l15 == 0 && row < M) out[row] = s + base;
        }
}

extern "C" void kernel_launch(void* const* d_in, const int* in_sizes, int n_in,
                              void* d_out, int out_size, void* d_ws, size_t ws_size,
                              hipStream_t stream) {
    const float* x   = (const float*)d_in[0];
    const int*   ei  = (const int*)d_in[1];
    const float* ew  = (const float*)d_in[2];
    const float* W1  = (const float*)d_in[3];
    const float* b1  = (const float*)d_in[4];
    const float* W2  = (const float*)d_in[5];
    const float* b2  = (const float*)d_in[6];
    const float* Wl1 = (const float*)d_in[7];
    const float* bl1 = (const float*)d_in[8];
    const float* Wl2 = (const float*)d_in[9];
    const float* bl2 = (const float*)d_in[10];
    float* out = (float*)d_out;
    const int N = in_sizes[0];
    const int E = in_sizes[2];

    const int nbuck = (N + (1 << BSHIFT) - 1) >> BSHIFT;      // 25
    const int cap = ((E / nbuck) * 5) / 4 + 1024;             // ~63sigma slack

    char* w = (char*)d_ws;
    size_t off = 0;
    auto alloc = [&](size_t bytes) -> void* {
        void* p = w + off;
        off = align256(off + bytes);
        return p;
    };
    uint*   g1     = (uint*)alloc((size_t)N * 64 * 4);      // bf16 [N][128]
    uint*   z      = (uint*)alloc((size_t)N * 64 * 4);      // bf16 [N][128]
    float*  dis    = (float*)alloc((size_t)N * 4);
    float*  p_     = (float*)alloc((size_t)N * 4);
    int*    cnt    = (int*)alloc((size_t)N * 4);
    int*    incl   = (int*)alloc((size_t)N * 4);
    int*    rowptr = (int*)alloc((size_t)(N + 1) * 4);
    int*    fill   = (int*)alloc((size_t)N * 4);
    int2*   cv     = (int2*)alloc((size_t)E * 8);
    uint2*  stg    = (uint2*)alloc((size_t)nbuck * cap * 8);
    int*    bfill  = (int*)alloc((size_t)nbuck * 4);
    ushort* Bt1    = (ushort*)alloc(32768 * 2);
    ushort* Bt2    = (ushort*)alloc(32768 * 2);
    const int nb = (N + 1023) / 1024;
    int*    bsum   = (int*)alloc((size_t)nb * 4);

    hipMemsetAsync(cnt, 0, (size_t)N * 4, stream);
    hipMemsetAsync(bfill, 0, (size_t)nbuck * 4, stream);
    k_part<<<(E + 1023) / 1024, 256, 0, stream>>>(ei, ew, cnt, bfill, stg, E, nbuck, cap);
    k_scan1<<<nb, 1024, 0, stream>>>(cnt, incl, bsum, N);
    k_scan2<<<1, 256, 0, stream>>>(bsum, nb);
    k_scan3<<<(N + 1 + 255) / 256, 256, 0, stream>>>(cnt, incl, bsum, rowptr, fill, N, E);
    k_fine<<<nbuck * 64, 256, 0, stream>>>(stg, bfill, rowptr, fill, cv, cap);
    k_prepB<<<128, 256, 0, stream>>>(W2, Wl1, Bt1, Bt2);
    k_deg_dis_p<<<(N + 3) / 4, 256, 0, stream>>>(rowptr, cv, x, dis, p_, N);
    k_q_g1<<<(N + 3) / 4, 256, 0, stream>>>(rowptr, cv, dis, p_, W1, b1, g1, N);
    k_agg<<<(N + 3) / 4, 256, 0, stream>>>(rowptr, cv, dis, g1, z, N);
    k_mlp<<<(N + 127) / 128, 256, 0, stream>>>((const ushort*)z, Bt1, Bt2,
                                               b2, bl1, Wl2, bl2, out, N);
}

// Round 6
// 329.273 us; speedup vs baseline: 1.3990x; 1.3990x over previous
//
#include <hip/hip_runtime.h>

// GCN on MI355X — round 6: single-owner bucket sort (kill write amplification).
//  - Round-5 failure analysis: 64 blocks/bucket spread each 512KB window over
//    all 8 non-coherent XCD L2s -> partial lines, WRITE_SIZE still 99 MB.
//  - Fix: 98 buckets of 1024 nodes, ONE block per bucket. LDS histogram +
//    LDS scan + LDS-ranked scatter into a private 128KB window (one L2 owner,
//    lines fill before eviction). k_fine also emits rowptr and fused deg/dis/p.
//  - Deleted: global cnt atomics, k_scan1/2/3, k_deg_dis_p, global fill[].
//  - Graph math (q_g1, agg) + fused MLP unchanged from round 4/5.

#define HD 128
#define HD2 256
#define BSHIFT 10            // 1024 nodes per bucket
#define BNODES 1024
#define SRCBITS 17           // N=100000 < 2^17

typedef __attribute__((ext_vector_type(8))) short bf8_t;   // 8 x bf16 (4 VGPR)
typedef __attribute__((ext_vector_type(4))) float f32x4;

static inline size_t align256(size_t x) { return (x + 255) & ~(size_t)255; }

__device__ inline ushort f2bf(float f) {            // RNE f32 -> bf16
    uint u = __float_as_uint(f);
    uint r = u + 0x7fffu + ((u >> 16) & 1u);
    return (ushort)(r >> 16);
}
__device__ inline float bflo(uint p) { return __uint_as_float(p << 16); }
__device__ inline float bfhi(uint p) { return __uint_as_float(p & 0xffff0000u); }
__device__ inline uint packbf(float a, float b) {
    return (uint)f2bf(a) | ((uint)f2bf(b) << 16);
}

// Phase 1: stream edges once, partition into 98 dst-buckets via LDS ranking.
// Staging writes are block-chunked runs (~21 edges/bucket/block = 168B).
__global__ __launch_bounds__(256) void k_part(const int* __restrict__ ei,
                                              const float* __restrict__ ew,
                                              int* __restrict__ bfill,
                                              uint2* __restrict__ stg,
                                              int E, int nbuck, int cap) {
    __shared__ int lcnt[128];
    __shared__ int lbase[128];
    int tid = threadIdx.x;
    for (int i = tid; i < nbuck; i += 256) lcnt[i] = 0;
    __syncthreads();
    bool is64 = (ei[1] == 0) && (ei[3] == 0) && (ei[5] == 0) && (ei[7] == 0);
    int e0 = blockIdx.x * 2048;
    uint pack[8]; uint wb[8]; int bkt[8]; int rank[8];
    for (int u = 0; u < 8; u++) {
        int e = e0 + u * 256 + tid;
        bkt[u] = -1;
        if (e < E) {
            int s, d;
            if (is64) { s = ei[2 * e]; d = ei[2 * (E + e)]; }
            else      { s = ei[e];     d = ei[E + e]; }
            bkt[u] = d >> BSHIFT;
            pack[u] = ((uint)(d & (BNODES - 1)) << SRCBITS) | (uint)s;
            wb[u] = __float_as_uint(ew[e]);
            rank[u] = atomicAdd(&lcnt[bkt[u]], 1);
        }
    }
    __syncthreads();
    for (int i = tid; i < nbuck; i += 256)
        lbase[i] = lcnt[i] ? atomicAdd(&bfill[i], lcnt[i]) : 0;
    __syncthreads();
    for (int u = 0; u < 8; u++)
        if (bkt[u] >= 0)
            stg[(size_t)bkt[u] * cap + lbase[bkt[u]] + rank[u]] =
                make_uint2(pack[u], wb[u]);
}

// Tiny scan over bucket totals; also rowptr[N] = E.
__global__ void k_bscan(const int* __restrict__ bfill, int* __restrict__ cvbase,
                        int* __restrict__ rowptr, int nbuck, int N, int E) {
    if (threadIdx.x == 0 && blockIdx.x == 0) {
        int run = 0;
        for (int i = 0; i < nbuck; i++) { cvbase[i] = run; run += bfill[i]; }
        rowptr[N] = E;
    }
}

// Phase 2: one block per bucket. LDS count -> LDS exclusive scan -> ranked
// scatter into the bucket's private ~128KB cv window (single L2 owner).
// Fused: rowptr emission + deg/dis/p for the bucket's nodes.
__global__ __launch_bounds__(256) void k_fine(const uint2* __restrict__ stg,
                                              const int* __restrict__ bfill,
                                              const int* __restrict__ cvbase,
                                              const float* __restrict__ x,
                                              float* __restrict__ dis,
                                              float* __restrict__ p,
                                              int* __restrict__ rowptr,
                                              int2* __restrict__ cv,
                                              int cap, int N) {
    __shared__ int cnt_l[BNODES];
    __shared__ int base_l[BNODES];
    __shared__ float degf[BNODES];
    __shared__ int wsum[4];
    int b = blockIdx.x, tid = threadIdx.x;
    int n = bfill[b];
    int cb = cvbase[b];
    const uint2* s = stg + (size_t)b * cap;
    for (int i = tid; i < BNODES; i += 256) { cnt_l[i] = 0; degf[i] = 1.0f; }
    __syncthreads();
    for (int i = tid; i < n; i += 256)
        atomicAdd(&cnt_l[s[i].x >> SRCBITS], 1);
    __syncthreads();
    // exclusive scan of cnt_l[0..1024): 4 elems/thread + wave scan + wave sums
    int a0 = cnt_l[4 * tid], a1 = cnt_l[4 * tid + 1];
    int a2 = cnt_l[4 * tid + 2], a3 = cnt_l[4 * tid + 3];
    int tsum = a0 + a1 + a2 + a3;
    int lane = tid & 63, wv = tid >> 6;
    int v = tsum;
    for (int off = 1; off < 64; off <<= 1) {
        int u = __shfl_up(v, off);
        if (lane >= off) v += u;
    }
    if (lane == 63) wsum[wv] = v;
    __syncthreads();
    int wpre = 0;
    for (int k = 0; k < wv; k++) wpre += wsum[k];
    int excl = v + wpre - tsum;
    base_l[4 * tid] = excl;
    base_l[4 * tid + 1] = excl + a0;
    base_l[4 * tid + 2] = excl + a0 + a1;
    base_l[4 * tid + 3] = excl + a0 + a1 + a2;
    cnt_l[4 * tid] = 0; cnt_l[4 * tid + 1] = 0;      // reuse as fill counters
    cnt_l[4 * tid + 2] = 0; cnt_l[4 * tid + 3] = 0;
    __syncthreads();
    for (int i = tid; i < n; i += 256) {
        uint2 r = s[i];
        int dl = r.x >> SRCBITS;
        int src = (int)(r.x & ((1u << SRCBITS) - 1));
        int pos = cb + base_l[dl] + atomicAdd(&cnt_l[dl], 1);
        cv[pos] = make_int2(src, (int)r.y);
        atomicAdd(&degf[dl], __uint_as_float(r.y));
    }
    __syncthreads();
    int g0 = b << BSHIFT;
    for (int dl = tid; dl < BNODES; dl += 256) {
        int gid = g0 + dl;
        if (gid < N) {
            rowptr[gid] = cb + base_l[dl];
            float r = rsqrtf(degf[dl]);
            dis[gid] = r;
            p[gid] = r * x[gid];
        }
    }
}

// Pre-transpose weights to bf16 chunk layout Bt[(k>>3)*NCOLS*8 + n*8 + (k&7)].
__global__ void k_prepB(const float* __restrict__ W2, const float* __restrict__ Wl1,
                        ushort* __restrict__ Bt1, ushort* __restrict__ Bt2) {
    int o = blockIdx.x * blockDim.x + threadIdx.x;
    if (o >= 32768) return;
    {   // Bt1: K=128, NCOLS=256
        int k0 = o & 7, n = (o >> 3) & 255, k8 = o >> 11;
        Bt1[o] = f2bf(W2[(size_t)(k8 * 8 + k0) * 256 + n]);
    }
    {   // Bt2: K=256, NCOLS=128
        int k0 = o & 7, n = (o >> 3) & 127, k8 = o >> 10;
        Bt2[o] = f2bf(Wl1[(size_t)(k8 * 8 + k0) * 128 + n]);
    }
}

// Wave per node, fused: q = sum(val*p[col]); t = dis*(q+p);
// g1[i][f] = dis * relu(t*W1[f]+b1[f]) stored bf16 (lane covers 2 feats).
__global__ __launch_bounds__(256) void k_q_g1(const int* __restrict__ rowptr,
                                              const int2* __restrict__ cv,
                                              const float* __restrict__ dis,
                                              const float* __restrict__ p,
                                              const float* __restrict__ W1,
                                              const float* __restrict__ b1,
                                              uint* __restrict__ g1, int N) {
    int wid = (blockIdx.x * blockDim.x + threadIdx.x) >> 6;
    int lane = threadIdx.x & 63;
    if (wid >= N) return;
    int beg = rowptr[wid], end = rowptr[wid + 1];
    float s = 0.0f;
    for (int i = beg + lane; i < end; i += 64) {
        int2 pr = cv[i];
        s += __int_as_float(pr.y) * p[pr.x];
    }
    for (int off = 32; off > 0; off >>= 1) s += __shfl_xor(s, off);
    float r = dis[wid];
    float t = r * (s + p[wid]);
    float2 wv = *(const float2*)(W1 + lane * 2);
    float2 bv = *(const float2*)(b1 + lane * 2);
    float ox = r * fmaxf(t * wv.x + bv.x, 0.0f);
    float oy = r * fmaxf(t * wv.y + bv.y, 0.0f);
    g1[(size_t)wid * 64 + lane] = packbf(ox, oy);
}

// Wave per node: z[d][:] = dis[d]*(sum_e w_e*g1[col_e][:] + g1[d][:]), bf16 io.
__global__ __launch_bounds__(256) void k_agg(const int* __restrict__ rowptr,
                                             const int2* __restrict__ cv,
                                             const float* __restrict__ dis,
                                             const uint* __restrict__ g1,
                                             uint* __restrict__ z, int N) {
    int wid = (blockIdx.x * blockDim.x + threadIdx.x) >> 6;
    int lane = threadIdx.x & 63;
    if (wid >= N) return;
    int beg = rowptr[wid], end = rowptr[wid + 1];
    float ax = 0.0f, ay = 0.0f;
    for (int base = beg; base < end; base += 64) {
        int eidx = base + lane;
        int2 pr = make_int2(0, 0);
        if (eidx < end) pr = cv[eidx];
        int cs = pr.x;
        float wv = __int_as_float(pr.y);
        int m = min(64, end - base);
        for (int j = 0; j < m; j++) {
            int s = __shfl(cs, j);
            float ww = __shfl(wv, j);
            uint gv = g1[(size_t)s * 64 + lane];
            ax += ww * bflo(gv);
            ay += ww * bfhi(gv);
        }
    }
    uint sv = g1[(size_t)wid * 64 + lane];
    float r = dis[wid];
    z[(size_t)wid * 64 + lane] = packbf(r * (ax + bflo(sv)), r * (ay + bfhi(sv)));
}

// Fused MLP: out[i] = relu(relu(z[i]@W2+b2)@Wl1+bl1) . wl2 + bl2.
// 4 independent waves/block, 32 rows each. h2 lives only in regs + per-wave LDS.
__global__ __launch_bounds__(256) void k_mlp(const ushort* __restrict__ A,    // z bf16 [N][128]
                                             const ushort* __restrict__ Bt1,  // [16][256][8]
                                             const ushort* __restrict__ Bt2,  // [32][128][8]
                                             const float* __restrict__ b2,
                                             const float* __restrict__ bl1,
                                             const float* __restrict__ wl2,
                                             const float* __restrict__ bl2,
                                             float* __restrict__ out, int M) {
    __shared__ ushort st[4][32][40];   // per-wave C->A staging; 80B row stride
    int tid = threadIdx.x;
    int wv = tid >> 6, lane = tid & 63;
    int l15 = lane & 15, quad = lane >> 4;
    int row0 = blockIdx.x * 128 + wv * 32;
    int r0 = row0 + l15;      r0 = r0 < M ? r0 : M - 1;   // clamp; stores guarded
    int r1 = row0 + 16 + l15; r1 = r1 < M ? r1 : M - 1;

    bf8_t a1[2][4];                       // all A1 frags resident (32 VGPR)
    for (int kc = 0; kc < 4; kc++) {
        a1[0][kc] = *(const bf8_t*)(A + (size_t)r0 * 128 + kc * 32 + quad * 8);
        a1[1][kc] = *(const bf8_t*)(A + (size_t)r1 * 128 + kc * 32 + quad * 8);
    }
    f32x4 acc2[2][8];
    for (int i = 0; i < 2; i++)
        for (int j = 0; j < 8; j++) acc2[i][j] = (f32x4){0.f, 0.f, 0.f, 0.f};

    for (int c = 0; c < 8; c++) {         // 32-col chunk of h2 == 32-k of GEMM2
        f32x4 acc1[2][2];
        for (int i = 0; i < 2; i++)
            for (int j = 0; j < 2; j++) acc1[i][j] = (f32x4){0.f, 0.f, 0.f, 0.f};
        for (int kc = 0; kc < 4; kc++)
            for (int nt = 0; nt < 2; nt++) {
                bf8_t b = *(const bf8_t*)(Bt1 +
                    ((size_t)(kc * 4 + quad) * 256 + c * 32 + nt * 16 + l15) * 8);
                acc1[0][nt] = __builtin_amdgcn_mfma_f32_16x16x32_bf16(a1[0][kc], b, acc1[0][nt], 0, 0, 0);
                acc1[1][nt] = __builtin_amdgcn_mfma_f32_16x16x32_bf16(a1[1][kc], b, acc1[1][nt], 0, 0, 0);
            }
        for (int nt = 0; nt < 2; nt++) {
            float bb = b2[c * 32 + nt * 16 + l15];
            for (int mt = 0; mt < 2; mt++)
                for (int rg = 0; rg < 4; rg++)
                    st[wv][mt * 16 + quad * 4 + rg][nt * 16 + l15] =
                        f2bf(fmaxf(acc1[mt][nt][rg] + bb, 0.f));
        }
        bf8_t a2_0 = *(const bf8_t*)&st[wv][l15][quad * 8];
        bf8_t a2_1 = *(const bf8_t*)&st[wv][16 + l15][quad * 8];
        for (int nt2 = 0; nt2 < 8; nt2++) {
            bf8_t b = *(const bf8_t*)(Bt2 +
                ((size_t)(c * 4 + quad) * 128 + nt2 * 16 + l15) * 8);
            acc2[0][nt2] = __builtin_amdgcn_mfma_f32_16x16x32_bf16(a2_0, b, acc2[0][nt2], 0, 0, 0);
            acc2[1][nt2] = __builtin_amdgcn_mfma_f32_16x16x32_bf16(a2_1, b, acc2[1][nt2], 0, 0, 0);
        }
    }
    float rs[2][4] = {};
    for (int nt2 = 0; nt2 < 8; nt2++) {
        int col = nt2 * 16 + l15;
        float bb = bl1[col], ww = wl2[col];
        for (int mt = 0; mt < 2; mt++)
            for (int rg = 0; rg < 4; rg++)
                rs[mt][rg] += fmaxf(acc2[mt][nt2][rg] + bb, 0.f) * ww;
    }
    float base = bl2[0];
    for (int mt = 0; mt < 2; mt++)
        for (int rg = 0; rg < 4; rg++) {
            float s = rs[mt][rg];
            s += __shfl_xor(s, 1);
            s += __shfl_xor(s, 2);
            s += __shfl_xor(s, 4);
            s += __shfl_xor(s, 8);
            int row = row0 + mt * 16 + quad * 4 + rg;
            if (l15 == 0 && row < M) out[row] = s + base;
        }
}

extern "C" void kernel_launch(void* const* d_in, const int* in_sizes, int n_in,
                              void* d_out, int out_size, void* d_ws, size_t ws_size,
                              hipStream_t stream) {
    const float* x   = (const float*)d_in[0];
    const int*   ei  = (const int*)d_in[1];
    const float* ew  = (const float*)d_in[2];
    const float* W1  = (const float*)d_in[3];
    const float* b1  = (const float*)d_in[4];
    const float* W2  = (const float*)d_in[5];
    const float* b2  = (const float*)d_in[6];
    const float* Wl1 = (const float*)d_in[7];
    const float* bl1 = (const float*)d_in[8];
    const float* Wl2 = (const float*)d_in[9];
    const float* bl2 = (const float*)d_in[10];
    float* out = (float*)d_out;
    const int N = in_sizes[0];
    const int E = in_sizes[2];

    const int nbuck = (N + BNODES - 1) >> BSHIFT;             // 98
    const int cap = ((E / nbuck) * 5) / 4 + 1024;             // ~32 sigma slack

    char* w = (char*)d_ws;
    size_t off = 0;
    auto alloc = [&](size_t bytes) -> void* {
        void* p = w + off;
        off = align256(off + bytes);
        return p;
    };
    uint*   g1     = (uint*)alloc((size_t)N * 64 * 4);      // bf16 [N][128]
    uint*   z      = (uint*)alloc((size_t)N * 64 * 4);      // bf16 [N][128]
    float*  dis    = (float*)alloc((size_t)N * 4);
    float*  p_     = (float*)alloc((size_t)N * 4);
    int*    rowptr = (int*)alloc((size_t)(N + 1) * 4);
    int2*   cv     = (int2*)alloc((size_t)E * 8);
    uint2*  stg    = (uint2*)alloc((size_t)nbuck * cap * 8);
    int*    bfill  = (int*)alloc(128 * 4);
    int*    cvbase = (int*)alloc(128 * 4);
    ushort* Bt1    = (ushort*)alloc(32768 * 2);
    ushort* Bt2    = (ushort*)alloc(32768 * 2);

    hipMemsetAsync(bfill, 0, 128 * 4, stream);
    k_part<<<(E + 2047) / 2048, 256, 0, stream>>>(ei, ew, bfill, stg, E, nbuck, cap);
    k_bscan<<<1, 64, 0, stream>>>(bfill, cvbase, rowptr, nbuck, N, E);
    k_fine<<<nbuck, 256, 0, stream>>>(stg, bfill, cvbase, x, dis, p_, rowptr, cv, cap, N);
    k_prepB<<<128, 256, 0, stream>>>(W2, Wl1, Bt1, Bt2);
    k_q_g1<<<(N + 3) / 4, 256, 0, stream>>>(rowptr, cv, dis, p_, W1, b1, g1, N);
    k_agg<<<(N + 3) / 4, 256, 0, stream>>>(rowptr, cv, dis, g1, z, N);
    k_mlp<<<(N + 127) / 128, 256, 0, stream>>>((const ushort*)z, Bt1, Bt2,
                                               b2, bl1, Wl2, bl2, out, N);
}

// Round 7
// 254.072 us; speedup vs baseline: 1.8131x; 1.2960x over previous
//
#include <hip/hip_runtime.h>

// GCN on MI355X — round 7: rank-1 reconstruction kills the k_agg row-gather.
//  - Round-6 profile: k_agg 108 us, FETCH 193 MB — bound by randomly
//    gathering 256B g1 rows (410 MB logical) per edge.
//  - Insight: g1[i][:] = dis[i]*relu(t[i]*W1[:]+b1[:]) is rank-1 in the
//    SCALAR t[i]. Gather the 8B (t,dis) pair instead (tp = 800 KB, fully
//    L2-resident) and reconstruct the 2 feats/lane with 3 VALU ops.
//    k_agg's inner loop is now pure VALU/shfl: 2 wave-loads per 64 edges.
//  - k_q: no longer writes g1 (25.6 MB saved); quarter-wave per node.
//  - Bucket sort (k_part/k_bscan/k_fine), prepB, fused MLP unchanged.

#define HD 128
#define HD2 256
#define BSHIFT 10            // 1024 nodes per bucket
#define BNODES 1024
#define SRCBITS 17           // N=100000 < 2^17

typedef __attribute__((ext_vector_type(8))) short bf8_t;   // 8 x bf16 (4 VGPR)
typedef __attribute__((ext_vector_type(4))) float f32x4;

static inline size_t align256(size_t x) { return (x + 255) & ~(size_t)255; }

__device__ inline ushort f2bf(float f) {            // RNE f32 -> bf16
    uint u = __float_as_uint(f);
    uint r = u + 0x7fffu + ((u >> 16) & 1u);
    return (ushort)(r >> 16);
}
__device__ inline uint packbf(float a, float b) {
    return (uint)f2bf(a) | ((uint)f2bf(b) << 16);
}

// Phase 1: stream edges once, partition into 98 dst-buckets via LDS ranking.
__global__ __launch_bounds__(256) void k_part(const int* __restrict__ ei,
                                              const float* __restrict__ ew,
                                              int* __restrict__ bfill,
                                              uint2* __restrict__ stg,
                                              int E, int nbuck, int cap) {
    __shared__ int lcnt[128];
    __shared__ int lbase[128];
    int tid = threadIdx.x;
    for (int i = tid; i < nbuck; i += 256) lcnt[i] = 0;
    __syncthreads();
    bool is64 = (ei[1] == 0) && (ei[3] == 0) && (ei[5] == 0) && (ei[7] == 0);
    int e0 = blockIdx.x * 2048;
    uint pack[8]; uint wb[8]; int bkt[8]; int rank[8];
    for (int u = 0; u < 8; u++) {
        int e = e0 + u * 256 + tid;
        bkt[u] = -1;
        if (e < E) {
            int s, d;
            if (is64) { s = ei[2 * e]; d = ei[2 * (E + e)]; }
            else      { s = ei[e];     d = ei[E + e]; }
            bkt[u] = d >> BSHIFT;
            pack[u] = ((uint)(d & (BNODES - 1)) << SRCBITS) | (uint)s;
            wb[u] = __float_as_uint(ew[e]);
            rank[u] = atomicAdd(&lcnt[bkt[u]], 1);
        }
    }
    __syncthreads();
    for (int i = tid; i < nbuck; i += 256)
        lbase[i] = lcnt[i] ? atomicAdd(&bfill[i], lcnt[i]) : 0;
    __syncthreads();
    for (int u = 0; u < 8; u++)
        if (bkt[u] >= 0)
            stg[(size_t)bkt[u] * cap + lbase[bkt[u]] + rank[u]] =
                make_uint2(pack[u], wb[u]);
}

// Tiny scan over bucket totals; also rowptr[N] = E.
__global__ void k_bscan(const int* __restrict__ bfill, int* __restrict__ cvbase,
                        int* __restrict__ rowptr, int nbuck, int N, int E) {
    if (threadIdx.x == 0 && blockIdx.x == 0) {
        int run = 0;
        for (int i = 0; i < nbuck; i++) { cvbase[i] = run; run += bfill[i]; }
        rowptr[N] = E;
    }
}

// Phase 2: one block per bucket. LDS count -> LDS scan -> ranked scatter into
// the bucket's private ~128KB cv window. Fused: rowptr + deg/dis/p.
__global__ __launch_bounds__(256) void k_fine(const uint2* __restrict__ stg,
                                              const int* __restrict__ bfill,
                                              const int* __restrict__ cvbase,
                                              const float* __restrict__ x,
                                              float* __restrict__ dis,
                                              float* __restrict__ p,
                                              int* __restrict__ rowptr,
                                              int2* __restrict__ cv,
                                              int cap, int N) {
    __shared__ int cnt_l[BNODES];
    __shared__ int base_l[BNODES];
    __shared__ float degf[BNODES];
    __shared__ int wsum[4];
    int b = blockIdx.x, tid = threadIdx.x;
    int n = bfill[b];
    int cb = cvbase[b];
    const uint2* s = stg + (size_t)b * cap;
    for (int i = tid; i < BNODES; i += 256) { cnt_l[i] = 0; degf[i] = 1.0f; }
    __syncthreads();
    for (int i = tid; i < n; i += 256)
        atomicAdd(&cnt_l[s[i].x >> SRCBITS], 1);
    __syncthreads();
    int a0 = cnt_l[4 * tid], a1 = cnt_l[4 * tid + 1];
    int a2 = cnt_l[4 * tid + 2], a3 = cnt_l[4 * tid + 3];
    int tsum = a0 + a1 + a2 + a3;
    int lane = tid & 63, wv = tid >> 6;
    int v = tsum;
    for (int off = 1; off < 64; off <<= 1) {
        int u = __shfl_up(v, off);
        if (lane >= off) v += u;
    }
    if (lane == 63) wsum[wv] = v;
    __syncthreads();
    int wpre = 0;
    for (int k = 0; k < wv; k++) wpre += wsum[k];
    int excl = v + wpre - tsum;
    base_l[4 * tid] = excl;
    base_l[4 * tid + 1] = excl + a0;
    base_l[4 * tid + 2] = excl + a0 + a1;
    base_l[4 * tid + 3] = excl + a0 + a1 + a2;
    cnt_l[4 * tid] = 0; cnt_l[4 * tid + 1] = 0;      // reuse as fill counters
    cnt_l[4 * tid + 2] = 0; cnt_l[4 * tid + 3] = 0;
    __syncthreads();
    for (int i = tid; i < n; i += 256) {
        uint2 r = s[i];
        int dl = r.x >> SRCBITS;
        int src = (int)(r.x & ((1u << SRCBITS) - 1));
        int pos = cb + base_l[dl] + atomicAdd(&cnt_l[dl], 1);
        cv[pos] = make_int2(src, (int)r.y);
        atomicAdd(&degf[dl], __uint_as_float(r.y));
    }
    __syncthreads();
    int g0 = b << BSHIFT;
    for (int dl = tid; dl < BNODES; dl += 256) {
        int gid = g0 + dl;
        if (gid < N) {
            rowptr[gid] = cb + base_l[dl];
            float r = rsqrtf(degf[dl]);
            dis[gid] = r;
            p[gid] = r * x[gid];
        }
    }
}

// Pre-transpose weights to bf16 chunk layout Bt[(k>>3)*NCOLS*8 + n*8 + (k&7)].
__global__ void k_prepB(const float* __restrict__ W2, const float* __restrict__ Wl1,
                        ushort* __restrict__ Bt1, ushort* __restrict__ Bt2) {
    int o = blockIdx.x * blockDim.x + threadIdx.x;
    if (o >= 32768) return;
    {   // Bt1: K=128, NCOLS=256
        int k0 = o & 7, n = (o >> 3) & 255, k8 = o >> 11;
        Bt1[o] = f2bf(W2[(size_t)(k8 * 8 + k0) * 256 + n]);
    }
    {   // Bt2: K=256, NCOLS=128
        int k0 = o & 7, n = (o >> 3) & 127, k8 = o >> 10;
        Bt2[o] = f2bf(Wl1[(size_t)(k8 * 8 + k0) * 128 + n]);
    }
}

// Quarter-wave per node: q = sum(val*p[col]); t = dis*(q+p); tp = (t, dis).
__global__ __launch_bounds__(256) void k_q(const int* __restrict__ rowptr,
                                           const int2* __restrict__ cv,
                                           const float* __restrict__ dis,
                                           const float* __restrict__ p,
                                           float2* __restrict__ tp, int N) {
    int gid = blockIdx.x * blockDim.x + threadIdx.x;
    int wid = gid >> 4;
    int sl = threadIdx.x & 15;
    if (wid >= N) return;
    int beg = rowptr[wid], end = rowptr[wid + 1];
    float s = 0.0f;
    for (int i = beg + sl; i < end; i += 16) {
        int2 pr = cv[i];
        s += __int_as_float(pr.y) * p[pr.x];
    }
    s += __shfl_xor(s, 1);
    s += __shfl_xor(s, 2);
    s += __shfl_xor(s, 4);
    s += __shfl_xor(s, 8);
    if (sl == 0) {
        float r = dis[wid];
        tp[wid] = make_float2(r * (s + p[wid]), r);
    }
}

// Wave per node, rank-1 reconstruction:
// z[d][:] = dis_d * ( sum_e w_e*dis_s*relu(t_s*W1[:]+b1[:]) + dis_d*relu(t_d*W1[:]+b1[:]) )
// Per 64-edge batch: 2 wave-loads (cv batch + tp gather), then pure VALU/shfl.
__global__ __launch_bounds__(256) void k_agg(const int* __restrict__ rowptr,
                                             const int2* __restrict__ cv,
                                             const float2* __restrict__ tp,
                                             const float* __restrict__ W1,
                                             const float* __restrict__ b1,
                                             uint* __restrict__ z, int N) {
    int wid = (blockIdx.x * blockDim.x + threadIdx.x) >> 6;
    int lane = threadIdx.x & 63;
    if (wid >= N) return;
    float2 w1 = *(const float2*)(W1 + lane * 2);
    float2 bb = *(const float2*)(b1 + lane * 2);
    int beg = rowptr[wid], end = rowptr[wid + 1];
    float ax = 0.0f, ay = 0.0f;
    for (int base = beg; base < end; base += 64) {
        int eidx = base + lane;
        int cs = 0;
        float wv = 0.0f;
        if (eidx < end) {
            int2 pr = cv[eidx];
            cs = pr.x;
            wv = __int_as_float(pr.y);
        }
        float2 tps = tp[cs];           // 8B gather, L2-resident (800 KB array)
        float wd = wv * tps.y;         // w_e * dis_src
        float tt = tps.x;              // t_src
        int m = min(64, end - base);
        for (int j = 0; j < m; j++) {
            float wdj = __shfl(wd, j);
            float tj  = __shfl(tt, j);
            float f0 = fmaxf(fmaf(tj, w1.x, bb.x), 0.0f);
            float f1 = fmaxf(fmaf(tj, w1.y, bb.y), 0.0f);
            ax = fmaf(wdj, f0, ax);
            ay = fmaf(wdj, f1, ay);
        }
    }
    float2 tpd = tp[wid];
    float rd = tpd.y;
    float s0 = rd * fmaxf(fmaf(tpd.x, w1.x, bb.x), 0.0f);   // g1[d] self term
    float s1 = rd * fmaxf(fmaf(tpd.x, w1.y, bb.y), 0.0f);
    z[(size_t)wid * 64 + lane] = packbf(rd * (ax + s0), rd * (ay + s1));
}

// Fused MLP: out[i] = relu(relu(z[i]@W2+b2)@Wl1+bl1) . wl2 + bl2.
// 4 independent waves/block, 32 rows each. h2 lives only in regs + per-wave LDS.
__global__ __launch_bounds__(256) void k_mlp(const ushort* __restrict__ A,    // z bf16 [N][128]
                                             const ushort* __restrict__ Bt1,  // [16][256][8]
                                             const ushort* __restrict__ Bt2,  // [32][128][8]
                                             const float* __restrict__ b2,
                                             const float* __restrict__ bl1,
                                             const float* __restrict__ wl2,
                                             const float* __restrict__ bl2,
                                             float* __restrict__ out, int M) {
    __shared__ ushort st[4][32][40];   // per-wave C->A staging; 80B row stride
    int tid = threadIdx.x;
    int wv = tid >> 6, lane = tid & 63;
    int l15 = lane & 15, quad = lane >> 4;
    int row0 = blockIdx.x * 128 + wv * 32;
    int r0 = row0 + l15;      r0 = r0 < M ? r0 : M - 1;   // clamp; stores guarded
    int r1 = row0 + 16 + l15; r1 = r1 < M ? r1 : M - 1;

    bf8_t a1[2][4];                       // all A1 frags resident (32 VGPR)
    for (int kc = 0; kc < 4; kc++) {
        a1[0][kc] = *(const bf8_t*)(A + (size_t)r0 * 128 + kc * 32 + quad * 8);
        a1[1][kc] = *(const bf8_t*)(A + (size_t)r1 * 128 + kc * 32 + quad * 8);
    }
    f32x4 acc2[2][8];
    for (int i = 0; i < 2; i++)
        for (int j = 0; j < 8; j++) acc2[i][j] = (f32x4){0.f, 0.f, 0.f, 0.f};

    for (int c = 0; c < 8; c++) {         // 32-col chunk of h2 == 32-k of GEMM2
        f32x4 acc1[2][2];
        for (int i = 0; i < 2; i++)
            for (int j = 0; j < 2; j++) acc1[i][j] = (f32x4){0.f, 0.f, 0.f, 0.f};
        for (int kc = 0; kc < 4; kc++)
            for (int nt = 0; nt < 2; nt++) {
                bf8_t b = *(const bf8_t*)(Bt1 +
                    ((size_t)(kc * 4 + quad) * 256 + c * 32 + nt * 16 + l15) * 8);
                acc1[0][nt] = __builtin_amdgcn_mfma_f32_16x16x32_bf16(a1[0][kc], b, acc1[0][nt], 0, 0, 0);
                acc1[1][nt] = __builtin_amdgcn_mfma_f32_16x16x32_bf16(a1[1][kc], b, acc1[1][nt], 0, 0, 0);
            }
        for (int nt = 0; nt < 2; nt++) {
            float bb = b2[c * 32 + nt * 16 + l15];
            for (int mt = 0; mt < 2; mt++)
                for (int rg = 0; rg < 4; rg++)
                    st[wv][mt * 16 + quad * 4 + rg][nt * 16 + l15] =
                        f2bf(fmaxf(acc1[mt][nt][rg] + bb, 0.f));
        }
        bf8_t a2_0 = *(const bf8_t*)&st[wv][l15][quad * 8];
        bf8_t a2_1 = *(const bf8_t*)&st[wv][16 + l15][quad * 8];
        for (int nt2 = 0; nt2 < 8; nt2++) {
            bf8_t b = *(const bf8_t*)(Bt2 +
                ((size_t)(c * 4 + quad) * 128 + nt2 * 16 + l15) * 8);
            acc2[0][nt2] = __builtin_amdgcn_mfma_f32_16x16x32_bf16(a2_0, b, acc2[0][nt2], 0, 0, 0);
            acc2[1][nt2] = __builtin_amdgcn_mfma_f32_16x16x32_bf16(a2_1, b, acc2[1][nt2], 0, 0, 0);
        }
    }
    float rs[2][4] = {};
    for (int nt2 = 0; nt2 < 8; nt2++) {
        int col = nt2 * 16 + l15;
        float bb = bl1[col], ww = wl2[col];
        for (int mt = 0; mt < 2; mt++)
            for (int rg = 0; rg < 4; rg++)
                rs[mt][rg] += fmaxf(acc2[mt][nt2][rg] + bb, 0.f) * ww;
    }
    float base = bl2[0];
    for (int mt = 0; mt < 2; mt++)
        for (int rg = 0; rg < 4; rg++) {
            float s = rs[mt][rg];
            s += __shfl_xor(s, 1);
            s += __shfl_xor(s, 2);
            s += __shfl_xor(s, 4);
            s += __shfl_xor(s, 8);
            int row = row0 + mt * 16 + quad * 4 + rg;
            if (l15 == 0 && row < M) out[row] = s + base;
        }
}

extern "C" void kernel_launch(void* const* d_in, const int* in_sizes, int n_in,
                              void* d_out, int out_size, void* d_ws, size_t ws_size,
                              hipStream_t stream) {
    const float* x   = (const float*)d_in[0];
    const int*   ei  = (const int*)d_in[1];
    const float* ew  = (const float*)d_in[2];
    const float* W1  = (const float*)d_in[3];
    const float* b1  = (const float*)d_in[4];
    const float* W2  = (const float*)d_in[5];
    const float* b2  = (const float*)d_in[6];
    const float* Wl1 = (const float*)d_in[7];
    const float* bl1 = (const float*)d_in[8];
    const float* Wl2 = (const float*)d_in[9];
    const float* bl2 = (const float*)d_in[10];
    float* out = (float*)d_out;
    const int N = in_sizes[0];
    const int E = in_sizes[2];

    const int nbuck = (N + BNODES - 1) >> BSHIFT;             // 98
    const int cap = ((E / nbuck) * 5) / 4 + 1024;             // ~32 sigma slack

    char* w = (char*)d_ws;
    size_t off = 0;
    auto alloc = [&](size_t bytes) -> void* {
        void* p = w + off;
        off = align256(off + bytes);
        return p;
    };
    uint*   z      = (uint*)alloc((size_t)N * 64 * 4);      // bf16 [N][128]
    float2* tp     = (float2*)alloc((size_t)N * 8);         // (t, dis)
    float*  dis    = (float*)alloc((size_t)N * 4);
    float*  p_     = (float*)alloc((size_t)N * 4);
    int*    rowptr = (int*)alloc((size_t)(N + 1) * 4);
    int2*   cv     = (int2*)alloc((size_t)E * 8);
    uint2*  stg    = (uint2*)alloc((size_t)nbuck * cap * 8);
    int*    bfill  = (int*)alloc(128 * 4);
    int*    cvbase = (int*)alloc(128 * 4);
    ushort* Bt1    = (ushort*)alloc(32768 * 2);
    ushort* Bt2    = (ushort*)alloc(32768 * 2);

    hipMemsetAsync(bfill, 0, 128 * 4, stream);
    k_part<<<(E + 2047) / 2048, 256, 0, stream>>>(ei, ew, bfill, stg, E, nbuck, cap);
    k_bscan<<<1, 64, 0, stream>>>(bfill, cvbase, rowptr, nbuck, N, E);
    k_fine<<<nbuck, 256, 0, stream>>>(stg, bfill, cvbase, x, dis, p_, rowptr, cv, cap, N);
    k_prepB<<<128, 256, 0, stream>>>(W2, Wl1, Bt1, Bt2);
    k_q<<<(N * 16 + 255) / 256, 256, 0, stream>>>(rowptr, cv, dis, p_, tp, N);
    k_agg<<<(N + 3) / 4, 256, 0, stream>>>(rowptr, cv, tp, W1, b1, z, N);
    k_mlp<<<(N + 127) / 128, 256, 0, stream>>>((const ushort*)z, Bt1, Bt2,
                                               b2, bl1, Wl2, bl2, out, N);
}